// Round 8
// baseline (279.852 us; speedup 1.0000x reference)
//
#include <hip/hip_runtime.h>

// ---------- types ----------
typedef __attribute__((ext_vector_type(8))) short bf16x8;   // 8 bf16 = 4 VGPRs
typedef __attribute__((ext_vector_type(4))) float f32x4;    // MFMA 16x16 acc

__device__ __forceinline__ unsigned short f2bf(float f) {
    union { float f; unsigned int u; } v; v.f = f;
    unsigned int u = v.u;
    u += 0x7fffu + ((u >> 16) & 1u);   // round-to-nearest-even
    return (unsigned short)(u >> 16);
}
__device__ __forceinline__ float bf2f(unsigned short s) {
    union { unsigned int u; float f; } v; v.u = ((unsigned int)s) << 16;
    return v.f;
}

// global -> LDS DMA, 16B per lane. LDS dest is wave-uniform base + lane*16.
__device__ __forceinline__ void gload16(const unsigned short* g, unsigned short* l) {
    __builtin_amdgcn_global_load_lds(
        (const __attribute__((address_space(1))) unsigned int*)(unsigned long long)(g),
        (__attribute__((address_space(3))) unsigned int*)(unsigned int)(unsigned long long)(l),
        16, 0, 0);
}

#define MFMA16(a, b, c) __builtin_amdgcn_mfma_f32_16x16x32_bf16((a), (b), (c), 0, 0, 0)

// ---------- dtype probe: flag=1 if inputs are fp32, 0 if bf16 ----------
__global__ __launch_bounds__(256) void detect_dtype(
    const unsigned short* __restrict__ x, int* __restrict__ flag) {
    __shared__ int red[4];
    const int t = threadIdx.x;
    int cnt = 0;
    #pragma unroll
    for (int i = 0; i < 16; i++) {
        const unsigned short v = x[t * 16 + i];
        const int e = (v >> 7) & 0xFF;
        cnt += (e >= 0xC8) ? 1 : 0;
    }
    #pragma unroll
    for (int off = 32; off; off >>= 1) cnt += __shfl_down(cnt, off);
    if ((t & 63) == 0) red[t >> 6] = cnt;
    __syncthreads();
    if (t == 0) *flag = (red[0] + red[1] + red[2] + red[3] >= 16) ? 1 : 0;
}

// ---------- x -> bf16 copy/convert ----------
__global__ __launch_bounds__(256) void convert_x(
    const void* __restrict__ xin, unsigned short* __restrict__ xb,
    const int* __restrict__ flag) {
    const long i = ((long)blockIdx.x * 256 + threadIdx.x) * 4;
    if (*flag) {
        const float4 v = *(const float4*)((const float*)xin + i);
        unsigned long long pk =  (unsigned long long)f2bf(v.x)
                              | ((unsigned long long)f2bf(v.y) << 16)
                              | ((unsigned long long)f2bf(v.z) << 32)
                              | ((unsigned long long)f2bf(v.w) << 48);
        *(unsigned long long*)(xb + i) = pk;
    } else {
        *(unsigned long long*)(xb + i) =
            *(const unsigned long long*)((const unsigned short*)xin + i);
    }
}

// ---------- weight transpose+convert ----------
__global__ __launch_bounds__(256) void transpose_convert(
    const void* __restrict__ W, unsigned short* __restrict__ Wt,
    const int* __restrict__ flag) {
    __shared__ unsigned short tile[32][33];
    const int tx = threadIdx.x & 31, ty = threadIdx.x >> 5;
    const int x0 = blockIdx.x * 32, y0 = blockIdx.y * 32;
    const int f = *flag;
    #pragma unroll
    for (int i = 0; i < 32; i += 8) {
        const long idx = (long)(y0 + ty + i) * 1024 + x0 + tx;
        tile[ty + i][tx] = f ? f2bf(((const float*)W)[idx])
                             : ((const unsigned short*)W)[idx];
    }
    __syncthreads();
    #pragma unroll
    for (int i = 0; i < 32; i += 8)
        Wt[(long)(x0 + ty + i) * 1024 + y0 + tx] = tile[tx][ty + i];
}

// ---------- 1024-vec -> bf16 ----------
__global__ __launch_bounds__(256) void convert_vec1024(
    const void* __restrict__ in, unsigned short* __restrict__ outv,
    const int* __restrict__ flag) {
    const int i = threadIdx.x * 4;
    if (*flag) {
        const float4 v = *(const float4*)((const float*)in + i);
        outv[i] = f2bf(v.x); outv[i+1] = f2bf(v.y);
        outv[i+2] = f2bf(v.z); outv[i+3] = f2bf(v.w);
    } else {
        *(unsigned long long*)(outv + i) =
            *(const unsigned long long*)((const unsigned short*)in + i);
    }
}

// ---------- bf16 GEMM: BMT x 256 tile, BK=64, DOUBLE-buffered, 0 intra-tile
// barriers (R7-validated).  C[n][m] = scale*(sum_k A[m][k]*Bt[n][k] + bias[m]).
// 512 threads = 8 waves (2M x 4N), wave tile (BMT/2)x64.
// R8 changes (theory: R7 time ~= LDS-port + MFMA-pipe SUM, not max):
//  1. __launch_bounds__(512,1): LDS already pins 1 block/CU; the old min=2
//     capped VGPR at 112 and forced read-burst/MFMA-burst serialization.
//  2. ks-sub-phase tile body: {read 8 frags -> 16 MFMA -> read 4 -> 16 MFMA}
//     x2 — next sub-phase's independent reads issue while the previous MFMA
//     cluster drains, overlapping LDS port with matrix pipe within a wave.
//  3. wave-parity ks order swap (even: ks0,ks1; odd: ks1,ks0) to decorrelate
//     port bursts across waves. acc indexing static in both paths.
// Slot-safety (R7): staging kt+1 -> buffer (kt+1)&1, last read in tile kt-1,
// sealed by that tile's end barrier -> safe anywhere in tile kt. One
// vmcnt(0)+s_barrier per K-tile (issued a full tile earlier -> ~no stall).
// Chunk swizzle (R3/R5/R6/R7-verified, 0 conflicts): chunk c of row r at
// slot c ^ (r&7) in the 128B row; inverse applied to the global DMA source.
// Epilogue: per-wave LDS bounce -> contiguous 256B store runs (R5/R7-verified).
template<int BMT>
__global__ __launch_bounds__(512, 1) void gemm_bt(
    const unsigned short* __restrict__ A, const unsigned short* __restrict__ Bt,
    unsigned short* __restrict__ C,
    int K, int lda, int ldb, int ldc,
    long strideAz, long strideBz, long strideCz,
    const unsigned short* __restrict__ bias, float scale) {

    // ---- XCD-aware bijective block remap (m204) ----
    const int gx = gridDim.x, gy = gridDim.y;
    const int nwg = gx * gy * (int)gridDim.z;
    int bid = (int)blockIdx.x + gx * ((int)blockIdx.y + gy * (int)blockIdx.z);
    {
        const int q = nwg >> 3, r = nwg & 7;
        const int xcd = bid & 7, idx = bid >> 3;
        bid = (xcd < r ? xcd * (q + 1) : r * (q + 1) + (xcd - r) * q) + idx;
    }
    const int bz  = bid / (gx * gy);
    const int rmd = bid - bz * gx * gy;
    const int by  = rmd / gx;
    const int bx  = rmd - by * gx;

    A  += (long)bz * strideAz;
    Bt += (long)bz * strideBz;
    C  += (long)bz * strideCz;

    constexpr int MI    = BMT / 32;              // acc M-repeats (8 or 4)
    constexpr int ACALL = BMT / 64;              // A stage calls (4 or 2)
    constexpr int ASH   = BMT * 64;              // A shorts per buffer
    constexpr int BUFSH = ASH + 16384;           // buffer stride in shorts
    __shared__ unsigned short lds[2 * BUFSH];    // 128 KiB / 96 KiB

    const int tid  = threadIdx.x;
    const int wave = tid >> 6;
    const int lane = tid & 63;
    const int quad = lane >> 4;
    const int lm   = lane & 15;
    const int wm   = (wave >> 2) * (BMT / 2);
    const int wn   = (wave & 3) * 64;

    const int m0 = by * BMT;
    const int n0 = bx * 256;

    // ---- staging: per gload16 call the wave covers 8 rows x 128B.
    // lane -> (row rl = wave*8 + lane>>3, slot lane&7); content chunk
    // = slot ^ (rl&7); rl&7 == (lane>>3)&7, invariant under +64-row calls.
    const int rl   = wave * 8 + (lane >> 3);
    const int ksrc = (((lane & 7) ^ ((lane >> 3) & 7)) << 3);   // elements
    const unsigned short* pA0 = A  + (long)(m0 + rl) * lda + ksrc;
    const unsigned short* pB0 = Bt + (long)(n0 + rl) * ldb + ksrc;
    const long sA1 = 64L * lda, sB1 = 64L * ldb;
    const int wofs = wave * 512;            // shorts (1 KiB per wave per call)

    // ---- fragment read slots: chunk (ks*4+quad) of row r at slot
    // (ks*4+quad) ^ (r&7); r&7 == lm&7 for all frag rows. ----
    const int sx8 = lm & 7;
    const int kq0 = ((quad ^ sx8) << 3);          // ks=0, shorts
    const int kq1 = (((4 + quad) ^ sx8) << 3);    // ks=1
    const int aro = (wm + lm) << 6;               // row*64 shorts
    const int bro = (wn + lm) << 6;

    f32x4 acc[MI][4];
    #pragma unroll
    for (int i = 0; i < MI; i++)
        #pragma unroll
        for (int j = 0; j < 4; j++) acc[i][j] = (f32x4){0.f, 0.f, 0.f, 0.f};

    const int NT = K >> 6;

#define STAGE(kt) do {                                                    \
        unsigned short* ab_ = &lds[((kt) & 1) * BUFSH + wofs];            \
        unsigned short* bb_ = ab_ + ASH;                                  \
        const unsigned short* ga_ = pA0 + (long)(kt) * 64;                \
        const unsigned short* gb_ = pB0 + (long)(kt) * 64;                \
        _Pragma("unroll")                                                 \
        for (int h = 0; h < ACALL; h++)                                   \
            gload16(ga_ + h * sA1, ab_ + h * 4096);                       \
        _Pragma("unroll")                                                 \
        for (int h = 0; h < 4; h++)                                       \
            gload16(gb_ + h * sB1, bb_ + h * 4096);                       \
    } while (0)

    // ---- prologue: tile0 staged, drained ----
    STAGE(0);
    asm volatile("s_waitcnt vmcnt(0)" ::: "memory");
    __builtin_amdgcn_s_barrier();

    for (int kt = 0; kt < NT; ++kt) {
        const unsigned short* ab = &lds[(kt & 1) * BUFSH];
        const unsigned short* bb = ab + ASH;

        // stage next tile into the other buffer (read-sealed at kt-1's end
        // barrier) — slot-safe anywhere in this tile, no barrier needed.
        if (kt + 1 < NT) STAGE(kt + 1);

        // one ks sub-phase: 8(+4) frag reads + 2x16 MFMA, acc statically
        // indexed; next sub-phase's reads overlap this one's MFMA drain.
        auto ksblk = [&](const int KQ) {
            bf16x8 aM[4], bN[4];
            #pragma unroll
            for (int i = 0; i < 4; i++)
                aM[i] = *(const bf16x8*)&ab[aro + (i << 10) + KQ];
            #pragma unroll
            for (int j = 0; j < 4; j++)
                bN[j] = *(const bf16x8*)&bb[bro + (j << 10) + KQ];
            __builtin_amdgcn_s_setprio(1);
            #pragma unroll
            for (int i = 0; i < 4; i++)
                #pragma unroll
                for (int j = 0; j < 4; j++)
                    acc[i][j] = MFMA16(aM[i], bN[j], acc[i][j]);
            __builtin_amdgcn_s_setprio(0);
            if constexpr (MI == 8) {
                bf16x8 aH[4];
                #pragma unroll
                for (int i = 0; i < 4; i++)
                    aH[i] = *(const bf16x8*)&ab[aro + ((i + 4) << 10) + KQ];
                __builtin_amdgcn_s_setprio(1);
                #pragma unroll
                for (int i = 0; i < 4; i++)
                    #pragma unroll
                    for (int j = 0; j < 4; j++)
                        acc[i + 4][j] = MFMA16(aH[i], bN[j], acc[i + 4][j]);
                __builtin_amdgcn_s_setprio(0);
            }
        };
        if ((wave & 1) == 0) { ksblk(kq0); ksblk(kq1); }
        else                 { ksblk(kq1); ksblk(kq0); }

        // single per-tile sync: next-tile DMA complete (issued a full tile
        // ago -> near-zero wait); barrier joins all waves.
        asm volatile("s_waitcnt vmcnt(0)" ::: "memory");
        __builtin_amdgcn_s_barrier();
    }
#undef STAGE

    // ---- epilogue: per-wave LDS bounce -> coalesced stores (R5/R7-verified).
    // acc[i][j][r] = C(n = wn + j*16+lm, m = wm + i*16+quad*4+r).
    // Wave region lds + wave*MI*1024 shorts = [64 n][MI*4 m-chunks of 8B],
    // chunk c at slot (c&~15)|((c&15)^(n&15)).  Loop's final barrier sealed
    // all reads; regions are wave-private.
    {
        unsigned short* ep = lds + wave * (MI * 1024);
        const int rowsh = MI * 16;                     // shorts per n-row
        #pragma unroll
        for (int i = 0; i < MI; i++) {
            float b4[4] = {0.f, 0.f, 0.f, 0.f};
            if (bias) {
                const unsigned short* bp = bias + m0 + wm + i * 16 + quad * 4;
                #pragma unroll
                for (int r = 0; r < 4; r++) b4[r] = bf2f(bp[r]);
            }
            const int c = i * 4 + quad;
            const int s = (c & ~15) | ((c & 15) ^ lm);
            #pragma unroll
            for (int j = 0; j < 4; j++) {
                unsigned long long pk = 0;
                #pragma unroll
                for (int r = 0; r < 4; r++)
                    pk |= (unsigned long long)f2bf((acc[i][j][r] + b4[r]) * scale) << (16 * r);
                *(unsigned long long*)&ep[(j * 16 + lm) * rowsh + (s << 2)] = pk;
            }
        }
        __builtin_amdgcn_s_barrier();
        // read back: lane covers chunk cc = lane&(4MI-1); 64/(4MI) rows/iter.
        const int cc = lane & (4 * MI - 1);
        #pragma unroll
        for (int it = 0; it < 4 * MI; it++) {
            const int n = it * (64 / (4 * MI)) + (lane / (4 * MI));
            const int sr = (cc & ~15) | ((cc & 15) ^ (n & 15));
            const unsigned long long v =
                *(const unsigned long long*)&ep[n * rowsh + (sr << 2)];
            *(unsigned long long*)&C[(long)(n0 + wn + n) * ldc + m0 + wm + cc * 4] = v;
        }
    }
}

// ---------- softmax ----------
__global__ __launch_bounds__(256) void softmax_rows(unsigned short* __restrict__ S, int rowlen) {
    __shared__ float red[4];
    const long row = blockIdx.x;
    unsigned short* p = S + row * rowlen;
    const int t = threadIdx.x;
    const int wave = t >> 6, lane = t & 63;

    uint4 raw = *(uint4*)(p + t * 8);
    unsigned short* u = (unsigned short*)&raw;
    float v[8], mx = -3.0e38f;
    #pragma unroll
    for (int i = 0; i < 8; i++) { v[i] = bf2f(u[i]); mx = fmaxf(mx, v[i]); }
    #pragma unroll
    for (int off = 32; off; off >>= 1) mx = fmaxf(mx, __shfl_down(mx, off));
    if (lane == 0) red[wave] = mx;
    __syncthreads();
    mx = fmaxf(fmaxf(red[0], red[1]), fmaxf(red[2], red[3]));
    __syncthreads();

    float s = 0.f;
    #pragma unroll
    for (int i = 0; i < 8; i++) { v[i] = __expf(v[i] - mx); s += v[i]; }
    #pragma unroll
    for (int off = 32; off; off >>= 1) s += __shfl_down(s, off);
    if (lane == 0) red[wave] = s;
    __syncthreads();
    s = red[0] + red[1] + red[2] + red[3];
    const float inv = 1.f / s;
    #pragma unroll
    for (int i = 0; i < 8; i++) u[i] = f2bf(v[i] * inv);
    *(uint4*)(p + t * 8) = raw;
}

// ---------- residual + LayerNorm, dual dtype ----------
__global__ __launch_bounds__(256) void resid_ln(
    const void* __restrict__ x, const unsigned short* __restrict__ attn,
    const void* __restrict__ gamma, const void* __restrict__ beta,
    void* __restrict__ out, const int* __restrict__ flag) {
    __shared__ float red[8];
    const long row = blockIdx.x;
    const int t = threadIdx.x;
    const int wave = t >> 6, lane = t & 63;
    const long base = row * 1024 + t * 4;
    const int f = *flag;

    uint2 ar = *(const uint2*)(attn + base);
    const unsigned short* au = (const unsigned short*)&ar;
    float h[4], s = 0.f, s2 = 0.f;
    if (f) {
        const float4 xr = *(const float4*)((const float*)x + base);
        h[0] = xr.x + bf2f(au[0]); h[1] = xr.y + bf2f(au[1]);
        h[2] = xr.z + bf2f(au[2]); h[3] = xr.w + bf2f(au[3]);
    } else {
        const uint2 xr = *(const uint2*)((const unsigned short*)x + base);
        const unsigned short* xu = (const unsigned short*)&xr;
        #pragma unroll
        for (int i = 0; i < 4; i++) h[i] = bf2f(xu[i]) + bf2f(au[i]);
    }
    #pragma unroll
    for (int i = 0; i < 4; i++) { s += h[i]; s2 += h[i] * h[i]; }
    #pragma unroll
    for (int off = 32; off; off >>= 1) { s += __shfl_down(s, off); s2 += __shfl_down(s2, off); }
    if (lane == 0) { red[wave] = s; red[4 + wave] = s2; }
    __syncthreads();
    s  = red[0] + red[1] + red[2] + red[3];
    s2 = red[4] + red[5] + red[6] + red[7];
    const float mu = s * (1.f / 1024.f);
    const float var = s2 * (1.f / 1024.f) - mu * mu;
    const float rstd = rsqrtf(var + 1e-3f);

    float g[4], bb[4];
    if (f) {
        const float4 gr = *(const float4*)((const float*)gamma + t * 4);
        const float4 br = *(const float4*)((const float*)beta  + t * 4);
        g[0]=gr.x; g[1]=gr.y; g[2]=gr.z; g[3]=gr.w;
        bb[0]=br.x; bb[1]=br.y; bb[2]=br.z; bb[3]=br.w;
    } else {
        #pragma unroll
        for (int i = 0; i < 4; i++) {
            g[i]  = bf2f(((const unsigned short*)gamma)[t * 4 + i]);
            bb[i] = bf2f(((const unsigned short*)beta)[t * 4 + i]);
        }
    }

    if (f) {
        float4 o;
        o.x = g[0]*(h[0]-mu)*rstd + bb[0];
        o.y = g[1]*(h[1]-mu)*rstd + bb[1];
        o.z = g[2]*(h[2]-mu)*rstd + bb[2];
        o.w = g[3]*(h[3]-mu)*rstd + bb[3];
        *(float4*)((float*)out + base) = o;
    } else {
        unsigned long long pk = 0;
        #pragma unroll
        for (int i = 0; i < 4; i++)
            pk |= (unsigned long long)f2bf(g[i]*(h[i]-mu)*rstd + bb[i]) << (16 * i);
        *(unsigned long long*)((unsigned short*)out + base) = pk;
    }
}

// ---------- launch ----------
extern "C" void kernel_launch(void* const* d_in, const int* in_sizes, int n_in,
                              void* d_out, int out_size, void* d_ws, size_t ws_size,
                              hipStream_t stream) {
    const void* x  = d_in[0];
    const void* Wq = d_in[1];
    const void* bq = d_in[2];
    const void* Wk = d_in[3];
    const void* bk = d_in[4];
    const void* Wv = d_in[5];
    const void* bv = d_in[6];
    const void* gamma = d_in[7];
    const void* beta  = d_in[8];

    // ws layout (bytes):
    //   xb / attn (reused):  0          (16,777,216)
    //   wt (Wq^T,Wk^T,Wv^T): 16,777,216 ( 6,291,456)
    //   bb (bq,bk,bv bf16):  23,068,672 (     6,144)
    //   flag:                23,074,816 (       128)
    //   qk [8192][2048]:     23,074,944 (33,554,432)  cols 0-1023=q, 1024-2047=k
    //   vt [1024][8192]:     56,629,376 (16,777,216)
    //   sc [4][2048][2048]:  73,406,592 (33,554,432)  -> end 106,961,024
    char* ws = (char*)d_ws;
    unsigned short* xb   = (unsigned short*)(ws);
    unsigned short* attn = (unsigned short*)(ws);
    unsigned short* wt   = (unsigned short*)(ws + 16777216L);
    unsigned short* bb   = (unsigned short*)(ws + 23068672L);
    int*            flag = (int*)(ws + 23074816L);
    unsigned short* qk   = (unsigned short*)(ws + 23074944L);
    unsigned short* vt   = (unsigned short*)(ws + 56629376L);
    unsigned short* sc   = (unsigned short*)(ws + 73406592L);

    const dim3 tb(256);
    const dim3 tg(512);
    detect_dtype<<<dim3(1), tb, 0, stream>>>((const unsigned short*)x, flag);
    convert_x<<<dim3(8192), tb, 0, stream>>>(x, xb, flag);
    transpose_convert<<<dim3(32, 32), tb, 0, stream>>>(Wq, wt, flag);
    transpose_convert<<<dim3(32, 32), tb, 0, stream>>>(Wk, wt + 1048576, flag);
    transpose_convert<<<dim3(32, 32), tb, 0, stream>>>(Wv, wt + 2097152, flag);
    convert_vec1024<<<dim3(1), tb, 0, stream>>>(bq, bb, flag);
    convert_vec1024<<<dim3(1), tb, 0, stream>>>(bk, bb + 1024, flag);
    convert_vec1024<<<dim3(1), tb, 0, stream>>>(bv, bb + 2048, flag);

    // Fused Q+K projection: qk[s][e'] = x @ [Wq|Wk] + [bq|bk]; m = e', n = s
    gemm_bt<256><<<dim3(32, 8, 1), tg, 0, stream>>>(wt, xb, qk,
        1024, 1024, 1024, 2048, 0L, 0L, 0L, bb, 1.0f);
    // V projection (transposed out): vt[d][s] = (x @ Wv)^T; m = s, n = d
    gemm_bt<128><<<dim3(4, 64, 1), tg, 0, stream>>>(xb, wt + 2097152, vt,
        1024, 1024, 1024, 8192, 0L, 0L, 0L, nullptr, 1.0f);
    // scores: sc[z][q][k] = (q_z . k_z) / 32; m = k, n = q
    gemm_bt<256><<<dim3(8, 8, 4), tg, 0, stream>>>(qk + 1024, qk, sc,
        1024, 2048, 2048, 2048, 4194304L, 4194304L, 4194304L, nullptr, 0.03125f);
    // P = softmax(sc) rows, in place
    softmax_rows<<<dim3(8192), tb, 0, stream>>>(sc, 2048);
    // attn[q][d] = P_z @ v_z + bv; m = d, n = q
    gemm_bt<128><<<dim3(8, 8, 4), tg, 0, stream>>>(vt, sc, attn,
        2048, 8192, 2048, 1024, 2048L, 4194304L, 2097152L, bb + 2048, 1.0f);
    // out = LN(x + attn)
    resid_ln<<<dim3(8192), tb, 0, stream>>>(x, attn, gamma, beta, d_out, flag);
}

// Round 10
// 268.233 us; speedup vs baseline: 1.0433x; 1.0433x over previous
//
#include <hip/hip_runtime.h>

// ---------- types ----------
typedef __attribute__((ext_vector_type(8))) short bf16x8;   // 8 bf16 = 4 VGPRs
typedef __attribute__((ext_vector_type(4))) float f32x4;    // MFMA 16x16 acc

__device__ __forceinline__ unsigned short f2bf(float f) {
    union { float f; unsigned int u; } v; v.f = f;
    unsigned int u = v.u;
    u += 0x7fffu + ((u >> 16) & 1u);   // round-to-nearest-even
    return (unsigned short)(u >> 16);
}
__device__ __forceinline__ float bf2f(unsigned short s) {
    union { unsigned int u; float f; } v; v.u = ((unsigned int)s) << 16;
    return v.f;
}

// global -> LDS DMA, 16B per lane. LDS dest is wave-uniform base + lane*16.
__device__ __forceinline__ void gload16(const unsigned short* g, unsigned short* l) {
    __builtin_amdgcn_global_load_lds(
        (const __attribute__((address_space(1))) unsigned int*)(unsigned long long)(g),
        (__attribute__((address_space(3))) unsigned int*)(unsigned int)(unsigned long long)(l),
        16, 0, 0);
}

#define MFMA16(a, b, c) __builtin_amdgcn_mfma_f32_16x16x32_bf16((a), (b), (c), 0, 0, 0)

// ---------- dtype probe: flag=1 if inputs are fp32, 0 if bf16 ----------
__global__ __launch_bounds__(256) void detect_dtype(
    const unsigned short* __restrict__ x, int* __restrict__ flag) {
    __shared__ int red[4];
    const int t = threadIdx.x;
    int cnt = 0;
    #pragma unroll
    for (int i = 0; i < 16; i++) {
        const unsigned short v = x[t * 16 + i];
        const int e = (v >> 7) & 0xFF;
        cnt += (e >= 0xC8) ? 1 : 0;
    }
    #pragma unroll
    for (int off = 32; off; off >>= 1) cnt += __shfl_down(cnt, off);
    if ((t & 63) == 0) red[t >> 6] = cnt;
    __syncthreads();
    if (t == 0) *flag = (red[0] + red[1] + red[2] + red[3] >= 16) ? 1 : 0;
}

// ---------- x -> bf16 copy/convert ----------
__global__ __launch_bounds__(256) void convert_x(
    const void* __restrict__ xin, unsigned short* __restrict__ xb,
    const int* __restrict__ flag) {
    const long i = ((long)blockIdx.x * 256 + threadIdx.x) * 4;
    if (*flag) {
        const float4 v = *(const float4*)((const float*)xin + i);
        unsigned long long pk =  (unsigned long long)f2bf(v.x)
                              | ((unsigned long long)f2bf(v.y) << 16)
                              | ((unsigned long long)f2bf(v.z) << 32)
                              | ((unsigned long long)f2bf(v.w) << 48);
        *(unsigned long long*)(xb + i) = pk;
    } else {
        *(unsigned long long*)(xb + i) =
            *(const unsigned long long*)((const unsigned short*)xin + i);
    }
}

// ---------- weight transpose+convert ----------
__global__ __launch_bounds__(256) void transpose_convert(
    const void* __restrict__ W, unsigned short* __restrict__ Wt,
    const int* __restrict__ flag) {
    __shared__ unsigned short tile[32][33];
    const int tx = threadIdx.x & 31, ty = threadIdx.x >> 5;
    const int x0 = blockIdx.x * 32, y0 = blockIdx.y * 32;
    const int f = *flag;
    #pragma unroll
    for (int i = 0; i < 32; i += 8) {
        const long idx = (long)(y0 + ty + i) * 1024 + x0 + tx;
        tile[ty + i][tx] = f ? f2bf(((const float*)W)[idx])
                             : ((const unsigned short*)W)[idx];
    }
    __syncthreads();
    #pragma unroll
    for (int i = 0; i < 32; i += 8)
        Wt[(long)(x0 + ty + i) * 1024 + y0 + tx] = tile[tx][ty + i];
}

// ---------- 1024-vec -> bf16 ----------
__global__ __launch_bounds__(256) void convert_vec1024(
    const void* __restrict__ in, unsigned short* __restrict__ outv,
    const int* __restrict__ flag) {
    const int i = threadIdx.x * 4;
    if (*flag) {
        const float4 v = *(const float4*)((const float*)in + i);
        outv[i] = f2bf(v.x); outv[i+1] = f2bf(v.y);
        outv[i+2] = f2bf(v.z); outv[i+3] = f2bf(v.w);
    } else {
        *(unsigned long long*)(outv + i) =
            *(const unsigned long long*)((const unsigned short*)in + i);
    }
}

// ---------- bf16 GEMM: BMT x 256 tile, BK=64, DOUBLE-buffered, 0 intra-tile
// barriers (R7-validated).  C[n][m] = scale*(sum_k A[m][k]*Bt[n][k] + bias[m]).
// 512 threads = 8 waves (2M x 4N), wave tile (BMT/2)x64.
// R9 change (theory: R8 per-tile time == MFMA + LDS-reads + DMA-writes SUM;
// zero port/pipe overlap because every wave's phase is read-burst ->
// lgkmcnt -> MFMA-burst in lockstep): explicit within-wave software
// pipeline — each MFMA cluster consumes fragments loaded ONE SUB-PHASE
// EARLIER, and the next sub-phase's ds_reads are issued BEFORE the cluster,
// so the compiler's counted lgkmcnt lets reads stream under MFMA.
//   pre:  read A-low(ks0), B(ks0)
//   ph1:  issue A-high(ks0) reads   -> MFMA(low , ks0)
//   ph2:  issue A-low(ks1)+B(ks1)   -> MFMA(high, ks0)
//   ph3:  issue A-high(ks1) reads   -> MFMA(low , ks1)
//   ph4:                            -> MFMA(high, ks1)
// Slot-safety (R7): staging kt+1 -> buffer (kt+1)&1, last read in tile kt-1,
// sealed by that tile's end barrier -> safe anywhere in tile kt. One
// vmcnt(0)+s_barrier per K-tile (issued a full tile earlier -> ~no stall).
// Chunk swizzle (R3..R8-verified, 0 conflicts): chunk c of row r at slot
// c ^ (r&7) in the 128B row; inverse applied to the global DMA source.
// Epilogue: per-wave LDS bounce -> contiguous 256B store runs (R5+-verified).
template<int BMT>
__global__ __launch_bounds__(512, 1) void gemm_bt(
    const unsigned short* __restrict__ A, const unsigned short* __restrict__ Bt,
    unsigned short* __restrict__ C,
    int K, int lda, int ldb, int ldc,
    long strideAz, long strideBz, long strideCz,
    const unsigned short* __restrict__ bias, float scale) {

    // ---- XCD-aware bijective block remap (m204) ----
    const int gx = gridDim.x, gy = gridDim.y;
    const int nwg = gx * gy * (int)gridDim.z;
    int bid = (int)blockIdx.x + gx * ((int)blockIdx.y + gy * (int)blockIdx.z);
    {
        const int q = nwg >> 3, r = nwg & 7;
        const int xcd = bid & 7, idx = bid >> 3;
        bid = (xcd < r ? xcd * (q + 1) : r * (q + 1) + (xcd - r) * q) + idx;
    }
    const int bz  = bid / (gx * gy);
    const int rmd = bid - bz * gx * gy;
    const int by  = rmd / gx;
    const int bx  = rmd - by * gx;

    A  += (long)bz * strideAz;
    Bt += (long)bz * strideBz;
    C  += (long)bz * strideCz;

    constexpr int MI    = BMT / 32;              // acc M-repeats (8 or 4)
    constexpr int ACALL = BMT / 64;              // A stage calls (4 or 2)
    constexpr int ASH   = BMT * 64;              // A shorts per buffer
    constexpr int BUFSH = ASH + 16384;           // buffer stride in shorts
    __shared__ unsigned short lds[2 * BUFSH];    // 128 KiB / 96 KiB

    const int tid  = threadIdx.x;
    const int wave = tid >> 6;
    const int lane = tid & 63;
    const int quad = lane >> 4;
    const int lm   = lane & 15;
    const int wm   = (wave >> 2) * (BMT / 2);
    const int wn   = (wave & 3) * 64;

    const int m0 = by * BMT;
    const int n0 = bx * 256;

    // ---- staging: per gload16 call the wave covers 8 rows x 128B.
    // lane -> (row rl = wave*8 + lane>>3, slot lane&7); content chunk
    // = slot ^ (rl&7); rl&7 == (lane>>3)&7, invariant under +64-row calls.
    const int rl   = wave * 8 + (lane >> 3);
    const int ksrc = (((lane & 7) ^ ((lane >> 3) & 7)) << 3);   // elements
    const unsigned short* pA0 = A  + (long)(m0 + rl) * lda + ksrc;
    const unsigned short* pB0 = Bt + (long)(n0 + rl) * ldb + ksrc;
    const long sA1 = 64L * lda, sB1 = 64L * ldb;
    const int wofs = wave * 512;            // shorts (1 KiB per wave per call)

    // ---- fragment read slots: chunk (ks*4+quad) of row r at slot
    // (ks*4+quad) ^ (r&7); r&7 == lm&7 for all frag rows. ----
    const int sx8 = lm & 7;
    const int kq0 = ((quad ^ sx8) << 3);          // ks=0, shorts
    const int kq1 = (((4 + quad) ^ sx8) << 3);    // ks=1
    const int aro = (wm + lm) << 6;               // row*64 shorts
    const int bro = (wn + lm) << 6;

    f32x4 acc[MI][4];
    #pragma unroll
    for (int i = 0; i < MI; i++)
        #pragma unroll
        for (int j = 0; j < 4; j++) acc[i][j] = (f32x4){0.f, 0.f, 0.f, 0.f};

    const int NT = K >> 6;

#define STAGE(kt) do {                                                    \
        unsigned short* ab_ = &lds[((kt) & 1) * BUFSH + wofs];            \
        unsigned short* bb_ = ab_ + ASH;                                  \
        const unsigned short* ga_ = pA0 + (long)(kt) * 64;                \
        const unsigned short* gb_ = pB0 + (long)(kt) * 64;                \
        _Pragma("unroll")                                                 \
        for (int h = 0; h < ACALL; h++)                                   \
            gload16(ga_ + h * sA1, ab_ + h * 4096);                       \
        _Pragma("unroll")                                                 \
        for (int h = 0; h < 4; h++)                                       \
            gload16(gb_ + h * sB1, bb_ + h * 4096);                       \
    } while (0)

    // ---- prologue: tile0 staged, drained ----
    STAGE(0);
    asm volatile("s_waitcnt vmcnt(0)" ::: "memory");
    __builtin_amdgcn_s_barrier();

    for (int kt = 0; kt < NT; ++kt) {
        const unsigned short* ab = &lds[(kt & 1) * BUFSH];
        const unsigned short* bb = ab + ASH;

        // stage next tile into the other buffer (read-sealed at kt-1's end
        // barrier) — slot-safe anywhere in this tile, no barrier needed.
        if (kt + 1 < NT) STAGE(kt + 1);

        if constexpr (MI == 8) {
            bf16x8 a0[4], ah0[4], a1[4], ah1[4], b0[4], b1[4];
            // pre-read: A-low ks0 + B ks0
            #pragma unroll
            for (int i = 0; i < 4; i++)
                a0[i] = *(const bf16x8*)&ab[aro + (i << 10) + kq0];
            #pragma unroll
            for (int j = 0; j < 4; j++)
                b0[j] = *(const bf16x8*)&bb[bro + (j << 10) + kq0];
            // phase 1: issue A-high ks0; MFMA (low, ks0)
            #pragma unroll
            for (int i = 0; i < 4; i++)
                ah0[i] = *(const bf16x8*)&ab[aro + ((i + 4) << 10) + kq0];
            __builtin_amdgcn_s_setprio(1);
            #pragma unroll
            for (int i = 0; i < 4; i++)
                #pragma unroll
                for (int j = 0; j < 4; j++)
                    acc[i][j] = MFMA16(a0[i], b0[j], acc[i][j]);
            __builtin_amdgcn_s_setprio(0);
            // phase 2: issue A-low ks1 + B ks1; MFMA (high, ks0)
            #pragma unroll
            for (int i = 0; i < 4; i++)
                a1[i] = *(const bf16x8*)&ab[aro + (i << 10) + kq1];
            #pragma unroll
            for (int j = 0; j < 4; j++)
                b1[j] = *(const bf16x8*)&bb[bro + (j << 10) + kq1];
            __builtin_amdgcn_s_setprio(1);
            #pragma unroll
            for (int i = 0; i < 4; i++)
                #pragma unroll
                for (int j = 0; j < 4; j++)
                    acc[i + 4][j] = MFMA16(ah0[i], b0[j], acc[i + 4][j]);
            __builtin_amdgcn_s_setprio(0);
            // phase 3: issue A-high ks1; MFMA (low, ks1)
            #pragma unroll
            for (int i = 0; i < 4; i++)
                ah1[i] = *(const bf16x8*)&ab[aro + ((i + 4) << 10) + kq1];
            __builtin_amdgcn_s_setprio(1);
            #pragma unroll
            for (int i = 0; i < 4; i++)
                #pragma unroll
                for (int j = 0; j < 4; j++)
                    acc[i][j] = MFMA16(a1[i], b1[j], acc[i][j]);
            __builtin_amdgcn_s_setprio(0);
            // phase 4: MFMA (high, ks1)
            __builtin_amdgcn_s_setprio(1);
            #pragma unroll
            for (int i = 0; i < 4; i++)
                #pragma unroll
                for (int j = 0; j < 4; j++)
                    acc[i + 4][j] = MFMA16(ah1[i], b1[j], acc[i + 4][j]);
            __builtin_amdgcn_s_setprio(0);
        } else {
            bf16x8 a0[4], a1[4], b0[4], b1[4];
            // pre-read: A ks0 + B ks0
            #pragma unroll
            for (int i = 0; i < 4; i++)
                a0[i] = *(const bf16x8*)&ab[aro + (i << 10) + kq0];
            #pragma unroll
            for (int j = 0; j < 4; j++)
                b0[j] = *(const bf16x8*)&bb[bro + (j << 10) + kq0];
            // phase 1: issue ks1 reads; MFMA ks0
            #pragma unroll
            for (int i = 0; i < 4; i++)
                a1[i] = *(const bf16x8*)&ab[aro + (i << 10) + kq1];
            #pragma unroll
            for (int j = 0; j < 4; j++)
                b1[j] = *(const bf16x8*)&bb[bro + (j << 10) + kq1];
            __builtin_amdgcn_s_setprio(1);
            #pragma unroll
            for (int i = 0; i < 4; i++)
                #pragma unroll
                for (int j = 0; j < 4; j++)
                    acc[i][j] = MFMA16(a0[i], b0[j], acc[i][j]);
            __builtin_amdgcn_s_setprio(0);
            // phase 2: MFMA ks1
            __builtin_amdgcn_s_setprio(1);
            #pragma unroll
            for (int i = 0; i < 4; i++)
                #pragma unroll
                for (int j = 0; j < 4; j++)
                    acc[i][j] = MFMA16(a1[i], b1[j], acc[i][j]);
            __builtin_amdgcn_s_setprio(0);
        }

        // single per-tile sync: next-tile DMA complete (issued a full tile
        // ago -> near-zero wait); barrier joins all waves.
        asm volatile("s_waitcnt vmcnt(0)" ::: "memory");
        __builtin_amdgcn_s_barrier();
    }
#undef STAGE

    // ---- epilogue: per-wave LDS bounce -> coalesced stores (R5/R7-verified).
    // acc[i][j][r] = C(n = wn + j*16+lm, m = wm + i*16+quad*4+r).
    // Wave region lds + wave*MI*1024 shorts = [64 n][MI*4 m-chunks of 8B],
    // chunk c at slot (c&~15)|((c&15)^(n&15)).  Loop's final barrier sealed
    // all reads; regions are wave-private.
    {
        unsigned short* ep = lds + wave * (MI * 1024);
        const int rowsh = MI * 16;                     // shorts per n-row
        #pragma unroll
        for (int i = 0; i < MI; i++) {
            float b4[4] = {0.f, 0.f, 0.f, 0.f};
            if (bias) {
                const unsigned short* bp = bias + m0 + wm + i * 16 + quad * 4;
                #pragma unroll
                for (int r = 0; r < 4; r++) b4[r] = bf2f(bp[r]);
            }
            const int c = i * 4 + quad;
            const int s = (c & ~15) | ((c & 15) ^ lm);
            #pragma unroll
            for (int j = 0; j < 4; j++) {
                unsigned long long pk = 0;
                #pragma unroll
                for (int r = 0; r < 4; r++)
                    pk |= (unsigned long long)f2bf((acc[i][j][r] + b4[r]) * scale) << (16 * r);
                *(unsigned long long*)&ep[(j * 16 + lm) * rowsh + (s << 2)] = pk;
            }
        }
        __builtin_amdgcn_s_barrier();
        // read back: lane covers chunk cc = lane&(4MI-1); 64/(4MI) rows/iter.
        const int cc = lane & (4 * MI - 1);
        #pragma unroll
        for (int it = 0; it < 4 * MI; it++) {
            const int n = it * (64 / (4 * MI)) + (lane / (4 * MI));
            const int sr = (cc & ~15) | ((cc & 15) ^ (n & 15));
            const unsigned long long v =
                *(const unsigned long long*)&ep[n * rowsh + (sr << 2)];
            *(unsigned long long*)&C[(long)(n0 + wn + n) * ldc + m0 + wm + cc * 4] = v;
        }
    }
}

// ---------- softmax ----------
__global__ __launch_bounds__(256) void softmax_rows(unsigned short* __restrict__ S, int rowlen) {
    __shared__ float red[4];
    const long row = blockIdx.x;
    unsigned short* p = S + row * rowlen;
    const int t = threadIdx.x;
    const int wave = t >> 6, lane = t & 63;

    uint4 raw = *(uint4*)(p + t * 8);
    unsigned short* u = (unsigned short*)&raw;
    float v[8], mx = -3.0e38f;
    #pragma unroll
    for (int i = 0; i < 8; i++) { v[i] = bf2f(u[i]); mx = fmaxf(mx, v[i]); }
    #pragma unroll
    for (int off = 32; off; off >>= 1) mx = fmaxf(mx, __shfl_down(mx, off));
    if (lane == 0) red[wave] = mx;
    __syncthreads();
    mx = fmaxf(fmaxf(red[0], red[1]), fmaxf(red[2], red[3]));
    __syncthreads();

    float s = 0.f;
    #pragma unroll
    for (int i = 0; i < 8; i++) { v[i] = __expf(v[i] - mx); s += v[i]; }
    #pragma unroll
    for (int off = 32; off; off >>= 1) s += __shfl_down(s, off);
    if (lane == 0) red[wave] = s;
    __syncthreads();
    s = red[0] + red[1] + red[2] + red[3];
    const float inv = 1.f / s;
    #pragma unroll
    for (int i = 0; i < 8; i++) u[i] = f2bf(v[i] * inv);
    *(uint4*)(p + t * 8) = raw;
}

// ---------- residual + LayerNorm, dual dtype ----------
__global__ __launch_bounds__(256) void resid_ln(
    const void* __restrict__ x, const unsigned short* __restrict__ attn,
    const void* __restrict__ gamma, const void* __restrict__ beta,
    void* __restrict__ out, const int* __restrict__ flag) {
    __shared__ float red[8];
    const long row = blockIdx.x;
    const int t = threadIdx.x;
    const int wave = t >> 6, lane = t & 63;
    const long base = row * 1024 + t * 4;
    const int f = *flag;

    uint2 ar = *(const uint2*)(attn + base);
    const unsigned short* au = (const unsigned short*)&ar;
    float h[4], s = 0.f, s2 = 0.f;
    if (f) {
        const float4 xr = *(const float4*)((const float*)x + base);
        h[0] = xr.x + bf2f(au[0]); h[1] = xr.y + bf2f(au[1]);
        h[2] = xr.z + bf2f(au[2]); h[3] = xr.w + bf2f(au[3]);
    } else {
        const uint2 xr = *(const uint2*)((const unsigned short*)x + base);
        const unsigned short* xu = (const unsigned short*)&xr;
        #pragma unroll
        for (int i = 0; i < 4; i++) h[i] = bf2f(xu[i]) + bf2f(au[i]);
    }
    #pragma unroll
    for (int i = 0; i < 4; i++) { s += h[i]; s2 += h[i] * h[i]; }
    #pragma unroll
    for (int off = 32; off; off >>= 1) { s += __shfl_down(s, off); s2 += __shfl_down(s2, off); }
    if (lane == 0) { red[wave] = s; red[4 + wave] = s2; }
    __syncthreads();
    s  = red[0] + red[1] + red[2] + red[3];
    s2 = red[4] + red[5] + red[6] + red[7];
    const float mu = s * (1.f / 1024.f);
    const float var = s2 * (1.f / 1024.f) - mu * mu;
    const float rstd = rsqrtf(var + 1e-3f);

    float g[4], bb[4];
    if (f) {
        const float4 gr = *(const float4*)((const float*)gamma + t * 4);
        const float4 br = *(const float4*)((const float*)beta  + t * 4);
        g[0]=gr.x; g[1]=gr.y; g[2]=gr.z; g[3]=gr.w;
        bb[0]=br.x; bb[1]=br.y; bb[2]=br.z; bb[3]=br.w;
    } else {
        #pragma unroll
        for (int i = 0; i < 4; i++) {
            g[i]  = bf2f(((const unsigned short*)gamma)[t * 4 + i]);
            bb[i] = bf2f(((const unsigned short*)beta)[t * 4 + i]);
        }
    }

    if (f) {
        float4 o;
        o.x = g[0]*(h[0]-mu)*rstd + bb[0];
        o.y = g[1]*(h[1]-mu)*rstd + bb[1];
        o.z = g[2]*(h[2]-mu)*rstd + bb[2];
        o.w = g[3]*(h[3]-mu)*rstd + bb[3];
        *(float4*)((float*)out + base) = o;
    } else {
        unsigned long long pk = 0;
        #pragma unroll
        for (int i = 0; i < 4; i++)
            pk |= (unsigned long long)f2bf(g[i]*(h[i]-mu)*rstd + bb[i]) << (16 * i);
        *(unsigned long long*)((unsigned short*)out + base) = pk;
    }
}

// ---------- launch ----------
extern "C" void kernel_launch(void* const* d_in, const int* in_sizes, int n_in,
                              void* d_out, int out_size, void* d_ws, size_t ws_size,
                              hipStream_t stream) {
    const void* x  = d_in[0];
    const void* Wq = d_in[1];
    const void* bq = d_in[2];
    const void* Wk = d_in[3];
    const void* bk = d_in[4];
    const void* Wv = d_in[5];
    const void* bv = d_in[6];
    const void* gamma = d_in[7];
    const void* beta  = d_in[8];

    // ws layout (bytes):
    //   xb / attn (reused):  0          (16,777,216)
    //   wt (Wq^T,Wk^T,Wv^T): 16,777,216 ( 6,291,456)
    //   bb (bq,bk,bv bf16):  23,068,672 (     6,144)
    //   flag:                23,074,816 (       128)
    //   qk [8192][2048]:     23,074,944 (33,554,432)  cols 0-1023=q, 1024-2047=k
    //   vt [1024][8192]:     56,629,376 (16,777,216)
    //   sc [4][2048][2048]:  73,406,592 (33,554,432)  -> end 106,961,024
    char* ws = (char*)d_ws;
    unsigned short* xb   = (unsigned short*)(ws);
    unsigned short* attn = (unsigned short*)(ws);
    unsigned short* wt   = (unsigned short*)(ws + 16777216L);
    unsigned short* bb   = (unsigned short*)(ws + 23068672L);
    int*            flag = (int*)(ws + 23074816L);
    unsigned short* qk   = (unsigned short*)(ws + 23074944L);
    unsigned short* vt   = (unsigned short*)(ws + 56629376L);
    unsigned short* sc   = (unsigned short*)(ws + 73406592L);

    const dim3 tb(256);
    const dim3 tg(512);
    detect_dtype<<<dim3(1), tb, 0, stream>>>((const unsigned short*)x, flag);
    convert_x<<<dim3(8192), tb, 0, stream>>>(x, xb, flag);
    transpose_convert<<<dim3(32, 32), tb, 0, stream>>>(Wq, wt, flag);
    transpose_convert<<<dim3(32, 32), tb, 0, stream>>>(Wk, wt + 1048576, flag);
    transpose_convert<<<dim3(32, 32), tb, 0, stream>>>(Wv, wt + 2097152, flag);
    convert_vec1024<<<dim3(1), tb, 0, stream>>>(bq, bb, flag);
    convert_vec1024<<<dim3(1), tb, 0, stream>>>(bk, bb + 1024, flag);
    convert_vec1024<<<dim3(1), tb, 0, stream>>>(bv, bb + 2048, flag);

    // Fused Q+K projection: qk[s][e'] = x @ [Wq|Wk] + [bq|bk]; m = e', n = s
    gemm_bt<256><<<dim3(32, 8, 1), tg, 0, stream>>>(wt, xb, qk,
        1024, 1024, 1024, 2048, 0L, 0L, 0L, bb, 1.0f);
    // V projection (transposed out): vt[d][s] = (x @ Wv)^T; m = s, n = d
    gemm_bt<128><<<dim3(4, 64, 1), tg, 0, stream>>>(xb, wt + 2097152, vt,
        1024, 1024, 1024, 8192, 0L, 0L, 0L, nullptr, 1.0f);
    // scores: sc[z][q][k] = (q_z . k_z) / 32; m = k, n = q
    gemm_bt<256><<<dim3(8, 8, 4), tg, 0, stream>>>(qk + 1024, qk, sc,
        1024, 2048, 2048, 2048, 4194304L, 4194304L, 4194304L, nullptr, 0.03125f);
    // P = softmax(sc) rows, in place
    softmax_rows<<<dim3(8192), tb, 0, stream>>>(sc, 2048);
    // attn[q][d] = P_z @ v_z + bv; m = d, n = q
    gemm_bt<128><<<dim3(8, 8, 4), tg, 0, stream>>>(vt, sc, attn,
        2048, 8192, 2048, 1024, 2048L, 4194304L, 2097152L, bb + 2048, 1.0f);
    // out = LN(x + attn)
    resid_ln<<<dim3(8192), tb, 0, stream>>>(x, attn, gamma, beta, d_out, flag);
}